// Round 10
// baseline (734.665 us; speedup 1.0000x reference)
//
#include <hip/hip_runtime.h>

#define V 196608
#define NNZ (9 * V)
#define B 4
#define FIN 32
#define FOUT 64
#define K 5
#define C 128            // FIN*B feature columns per vertex
#define ROWU 64          // uints per bf16 row (128 feats * 2B / 4B)
#define SPMM_BLOCKS 2048 // persistent grid: 8 blocks/CU * 256 CU

typedef __attribute__((ext_vector_type(8))) short bf16x8;
typedef __attribute__((ext_vector_type(4))) float f32x4;

// ---- bf16 helpers (bit-level, RNE) ---------------------------------------
static __device__ __forceinline__ unsigned int f2bf(float f) {
    union { float f; unsigned int u; } v; v.f = f;
    return (v.u + 0x7FFFu + ((v.u >> 16) & 1u)) >> 16;
}
static __device__ __forceinline__ float bflo(unsigned int u) {
    union { unsigned int u; float f; } v; v.u = u << 16; return v.f;
}
static __device__ __forceinline__ float bfhi(unsigned int u) {
    union { unsigned int u; float f; } v; v.u = u & 0xFFFF0000u; return v.f;
}

// ---------------------------------------------------------------------------
// fast zero for cursor: V ints = 48K uint4
__global__ void zero_cursor(uint4* __restrict__ p) {
    int t = blockIdx.x * 256 + threadIdx.x;
    if (t < V / 4) p[t] = (uint4){0u, 0u, 0u, 0u};
}

// ---------------------------------------------------------------------------
// x0[v][b*32+fin] (bf16, b-major row), vectorized: thread = one uint4 (8 feats)
__global__ void build_x0(const float* __restrict__ inp, uint4* __restrict__ x0v) {
    int t = blockIdx.x * 256 + threadIdx.x;
    if (t >= V * 16) return;
    int v = t >> 4;
    int seg = t & 15;   // seg covers dwords seg*4..+3 = b*16 + q*4 + 0..3
    int b = seg >> 2;
    int q = seg & 3;
    const float4* s = reinterpret_cast<const float4*>(inp + ((size_t)b * V + v) * 32 + q * 8);
    float4 fa = s[0], fb = s[1];
    uint4 u;
    u.x = f2bf(fa.x) | (f2bf(fa.y) << 16);
    u.y = f2bf(fa.z) | (f2bf(fa.w) << 16);
    u.z = f2bf(fb.x) | (f2bf(fb.y) << 16);
    u.w = f2bf(fb.z) | (f2bf(fb.w) << 16);
    x0v[(size_t)v * 16 + seg] = u;
}

// ---------------------------------------------------------------------------
// W fragment prep: split-precision bf16 B-fragments, k-major K ordering.
__global__ void build_wfrag(const float* __restrict__ w, uint4* __restrict__ wfh,
                            uint4* __restrict__ wfl) {
    int idx = blockIdx.x * 256 + threadIdx.x;
    if (idx >= K * 4 * 64) return;
    int lane = idx & 63;
    int nt = (idx >> 6) & 3;
    int k = idx >> 8;
    int col = lane & 15;
    int quad = lane >> 4;
    int o = nt * 16 + col;
    unsigned int hh[8], ll[8];
#pragma unroll
    for (int e = 0; e < 8; ++e) {
        int fin = quad * 8 + e;
        float wv = w[(fin * 5 + k) * 64 + o];
        unsigned int hb = f2bf(wv);
        float hf = bflo(hb);
        ll[e] = f2bf(wv - hf);
        hh[e] = hb;
    }
    uint4 uh, ul;
    uh.x = hh[0] | (hh[1] << 16);
    uh.y = hh[2] | (hh[3] << 16);
    uh.z = hh[4] | (hh[5] << 16);
    uh.w = hh[6] | (hh[7] << 16);
    ul.x = ll[0] | (ll[1] << 16);
    ul.y = ll[2] | (ll[3] << 16);
    ul.z = ll[4] | (ll[5] << 16);
    ul.w = ll[6] | (ll[7] << 16);
    wfh[idx] = uh;
    wfl[idx] = ul;
}

// ---------------------------------------------------------------------------
// CSR build step 1: histogram row counts into cnt[] (pre-zeroed)
__global__ void hist_rows(const int* __restrict__ rows, int* __restrict__ cnt) {
    int e = blockIdx.x * 256 + threadIdx.x;
    if (e < NNZ) atomicAdd(&cnt[rows[e]], 1);
}

// ---------------------------------------------------------------------------
// parallel scan phase A: per-1024-chunk sums
__global__ void chunk_sums(const int* __restrict__ cnt, int* __restrict__ bsum) {
    __shared__ int ws[16];
    int tid = threadIdx.x;
    int lane = tid & 63;
    int wid = tid >> 6;
    int v = cnt[blockIdx.x * 1024 + tid];
#pragma unroll
    for (int off = 32; off >= 1; off >>= 1) v += __shfl_down(v, off, 64);
    if (lane == 0) ws[wid] = v;
    __syncthreads();
    if (tid < 16) {
        int s = ws[tid];
#pragma unroll
        for (int off = 8; off >= 1; off >>= 1) s += __shfl_down(s, off, 16);
        if (tid == 0) bsum[blockIdx.x] = s;
    }
}

// ---------------------------------------------------------------------------
// parallel scan phase B: exclusive scan of 192 chunk sums
__global__ void scan_sums(const int* __restrict__ bsum, int* __restrict__ bpre,
                          int* __restrict__ rowptr) {
    __shared__ int ws[4];
    int tid = threadIdx.x;
    int lane = tid & 63;
    int wid = tid >> 6;
    int v = (tid < 192) ? bsum[tid] : 0;
    int x = v;
#pragma unroll
    for (int off = 1; off < 64; off <<= 1) {
        int t = __shfl_up(x, off, 64);
        if (lane >= off) x += t;
    }
    if (lane == 63) ws[wid] = x;
    __syncthreads();
    if (wid == 0 && lane < 4) {
        int s = ws[lane];
        int y = s;
#pragma unroll
        for (int off = 1; off < 4; off <<= 1) {
            int t = __shfl_up(y, off, 4);
            if (lane >= off) y += t;
        }
        ws[lane] = y - s;
    }
    __syncthreads();
    int incl = x + ws[wid];
    if (tid < 192) bpre[tid] = incl - v;
    if (tid == 191) rowptr[V] = incl;
}

// ---------------------------------------------------------------------------
// parallel scan phase C: per-chunk scan + chunk prefix
__global__ void scan_chunks(const int* __restrict__ cnt, const int* __restrict__ bpre,
                            int* __restrict__ rowptr, int* __restrict__ cursor) {
    __shared__ int wsum[16];
    int tid = threadIdx.x;
    int lane = tid & 63;
    int wid = tid >> 6;
    int base = blockIdx.x * 1024;
    int v = cnt[base + tid];
    int x = v;
#pragma unroll
    for (int off = 1; off < 64; off <<= 1) {
        int t = __shfl_up(x, off, 64);
        if (lane >= off) x += t;
    }
    if (lane == 63) wsum[wid] = x;
    __syncthreads();
    if (wid == 0 && lane < 16) {
        int s = wsum[lane];
        int y = s;
#pragma unroll
        for (int off = 1; off < 16; off <<= 1) {
            int t = __shfl_up(y, off, 16);
            if (lane >= off) y += t;
        }
        wsum[lane] = y - s;
    }
    __syncthreads();
    int excl = x - v + wsum[wid] + bpre[blockIdx.x];
    rowptr[base + tid] = excl;
    cursor[base + tid] = excl;
}

// ---------------------------------------------------------------------------
// windowed CSR scatter: pass only handles rows in [lo, hi) so cev writes and
// cursor atomics concentrate in an L2-hot window (kills 64B-line write amp).
__global__ void scatter_edges_win(const int* __restrict__ rows, const int* __restrict__ cols,
                                  const float* __restrict__ vals, int* __restrict__ cursor,
                                  int2* __restrict__ cev, int lo, int hi) {
    int e = blockIdx.x * 256 + threadIdx.x;
    if (e >= NNZ) return;
    int r = rows[e];
    if (r < lo || r >= hi) return;
    int p = atomicAdd(&cursor[r], 1);
    int2 pk;
    pk.x = cols[e];
    pk.y = __float_as_int(vals[e]);
    cev[p] = pk;
}

// ---------------------------------------------------------------------------
// bf16 gather SpMM v3 (reverted, proven): persistent waves, 2 rows per
// iteration, joint 4+4 strip-mine -> up to 8 gathers in flight per wave.
template <int COMBINE>
__global__ __launch_bounds__(256) void spmm_gather(
    const int* __restrict__ rowptr, const int2* __restrict__ cev,
    const unsigned int* __restrict__ x, const unsigned int* __restrict__ xm2,
    unsigned int* __restrict__ y) {
    const int lane = threadIdx.x & 63;
    const int wid0 = (blockIdx.x * 256 + threadIdx.x) >> 6;
    const int NW = SPMM_BLOCKS * 4;  // total waves
    for (int base = wid0 * 2; base < V; base += NW * 2) {
        const int r0 = base, r1 = base + 1;
        const int s0 = rowptr[r0];
        const int e0 = rowptr[r0 + 1];
        const int e1 = rowptr[r1 + 1];  // s1 == e0
        float ax0 = 0.f, ay0 = 0.f, ax1 = 0.f, ay1 = 0.f;
        int i0 = s0, i1 = e0;
        while (e0 - i0 >= 4 && e1 - i1 >= 4) {
            int2 Ea[4], Eb[4];
#pragma unroll
            for (int j = 0; j < 4; ++j) {
                Ea[j] = cev[i0 + j];
                Eb[j] = cev[i1 + j];
            }
            unsigned int Ua[4], Ub[4];
#pragma unroll
            for (int j = 0; j < 4; ++j) {
                Ua[j] = x[(size_t)Ea[j].x * ROWU + lane];
                Ub[j] = x[(size_t)Eb[j].x * ROWU + lane];
            }
#pragma unroll
            for (int j = 0; j < 4; ++j) {
                float va = __int_as_float(Ea[j].y);
                float vb = __int_as_float(Eb[j].y);
                ax0 = fmaf(va, bflo(Ua[j]), ax0);
                ay0 = fmaf(va, bfhi(Ua[j]), ay0);
                ax1 = fmaf(vb, bflo(Ub[j]), ax1);
                ay1 = fmaf(vb, bfhi(Ub[j]), ay1);
            }
            i0 += 4;
            i1 += 4;
        }
        for (; i0 + 2 <= e0; i0 += 2) {
            int2 a = cev[i0], b = cev[i0 + 1];
            unsigned int u0 = x[(size_t)a.x * ROWU + lane];
            unsigned int u1 = x[(size_t)b.x * ROWU + lane];
            float v0 = __int_as_float(a.y), v1 = __int_as_float(b.y);
            ax0 = fmaf(v0, bflo(u0), ax0);
            ay0 = fmaf(v0, bfhi(u0), ay0);
            ax0 = fmaf(v1, bflo(u1), ax0);
            ay0 = fmaf(v1, bfhi(u1), ay0);
        }
        for (; i0 < e0; ++i0) {
            int2 a = cev[i0];
            unsigned int u = x[(size_t)a.x * ROWU + lane];
            float v = __int_as_float(a.y);
            ax0 = fmaf(v, bflo(u), ax0);
            ay0 = fmaf(v, bfhi(u), ay0);
        }
        for (; i1 + 2 <= e1; i1 += 2) {
            int2 a = cev[i1], b = cev[i1 + 1];
            unsigned int u0 = x[(size_t)a.x * ROWU + lane];
            unsigned int u1 = x[(size_t)b.x * ROWU + lane];
            float v0 = __int_as_float(a.y), v1 = __int_as_float(b.y);
            ax1 = fmaf(v0, bflo(u0), ax1);
            ay1 = fmaf(v0, bfhi(u0), ay1);
            ax1 = fmaf(v1, bflo(u1), ax1);
            ay1 = fmaf(v1, bfhi(u1), ay1);
        }
        for (; i1 < e1; ++i1) {
            int2 a = cev[i1];
            unsigned int u = x[(size_t)a.x * ROWU + lane];
            float v = __int_as_float(a.y);
            ax1 = fmaf(v, bflo(u), ax1);
            ay1 = fmaf(v, bfhi(u), ay1);
        }
        if (COMBINE) {
            unsigned int m0 = xm2[(size_t)r0 * ROWU + lane];
            unsigned int m1 = xm2[(size_t)r1 * ROWU + lane];
            ax0 = 2.0f * ax0 - bflo(m0);
            ay0 = 2.0f * ay0 - bfhi(m0);
            ax1 = 2.0f * ax1 - bflo(m1);
            ay1 = 2.0f * ay1 - bfhi(m1);
        }
        y[(size_t)r0 * ROWU + lane] = f2bf(ax0) | (f2bf(ay0) << 16);
        y[(size_t)r1 * ROWU + lane] = f2bf(ax1) | (f2bf(ay1) << 16);
    }
}

// ---------------------------------------------------------------------------
// FUSED last-SpMM + MFMA contraction. Block = 64 vertices (4 waves x 16).
// Phase 1 (per wave, its own 16 rows): x4 = 2*L*x3 - x2, spmm-v3-style paired
//   gather, packed bf16 rows into LDS with per-row dword rotation
//   (d + 4*row) & 63  -> breaks the 256B-stride bank conflict to <=2-way.
// Phase 2: MFMA contraction; k=0..3 A-frags from global, k=4 from LDS.
//   Same-wave LDS produce->consume: no barrier needed.
// A-frag: lane l holds x[v0+(l&15)][b*32 + (l>>4)*8 .. +8]
// C/D:    col=lane&15, row=(lane>>4)*4+reg   [m89-verified mapping]
__global__ __launch_bounds__(256) void fused_mfma(
    const unsigned int* __restrict__ x0, const unsigned int* __restrict__ x1,
    const unsigned int* __restrict__ x2, const unsigned int* __restrict__ x3,
    const int* __restrict__ rowptr, const int2* __restrict__ cev,
    const uint4* __restrict__ wfh, const uint4* __restrict__ wfl,
    const float* __restrict__ bias, float* __restrict__ out) {
    __shared__ unsigned int lx4[64 * 64];  // 16 KB: block's 64 x4 rows, rotated
    const int tid = threadIdx.x;
    const int lane = tid & 63;
    const int wid = tid >> 6;
    const int gv0 = blockIdx.x * 64;   // block vertex base
    const int wv0 = gv0 + wid * 16;    // this wave's 16 rows (phase 1 AND 2)

    // ---- phase 1: x4 rows for wv0..wv0+15 into LDS ----
    for (int p = 0; p < 8; ++p) {
        const int r0 = wv0 + 2 * p, r1 = r0 + 1;
        const int s0 = rowptr[r0];
        const int e0 = rowptr[r0 + 1];
        const int e1 = rowptr[r1 + 1];
        float ax0 = 0.f, ay0 = 0.f, ax1 = 0.f, ay1 = 0.f;
        int i0 = s0, i1 = e0;
        while (e0 - i0 >= 4 && e1 - i1 >= 4) {
            int2 Ea[4], Eb[4];
#pragma unroll
            for (int j = 0; j < 4; ++j) {
                Ea[j] = cev[i0 + j];
                Eb[j] = cev[i1 + j];
            }
            unsigned int Ua[4], Ub[4];
#pragma unroll
            for (int j = 0; j < 4; ++j) {
                Ua[j] = x3[(size_t)Ea[j].x * ROWU + lane];
                Ub[j] = x3[(size_t)Eb[j].x * ROWU + lane];
            }
#pragma unroll
            for (int j = 0; j < 4; ++j) {
                float va = __int_as_float(Ea[j].y);
                float vb = __int_as_float(Eb[j].y);
                ax0 = fmaf(va, bflo(Ua[j]), ax0);
                ay0 = fmaf(va, bfhi(Ua[j]), ay0);
                ax1 = fmaf(vb, bflo(Ub[j]), ax1);
                ay1 = fmaf(vb, bfhi(Ub[j]), ay1);
            }
            i0 += 4;
            i1 += 4;
        }
        for (; i0 < e0; ++i0) {
            int2 a = cev[i0];
            unsigned int u = x3[(size_t)a.x * ROWU + lane];
            float v = __int_as_float(a.y);
            ax0 = fmaf(v, bflo(u), ax0);
            ay0 = fmaf(v, bfhi(u), ay0);
        }
        for (; i1 < e1; ++i1) {
            int2 a = cev[i1];
            unsigned int u = x3[(size_t)a.x * ROWU + lane];
            float v = __int_as_float(a.y);
            ax1 = fmaf(v, bflo(u), ax1);
            ay1 = fmaf(v, bfhi(u), ay1);
        }
        unsigned int m0 = x2[(size_t)r0 * ROWU + lane];
        unsigned int m1 = x2[(size_t)r1 * ROWU + lane];
        ax0 = 2.0f * ax0 - bflo(m0);
        ay0 = 2.0f * ay0 - bfhi(m0);
        ax1 = 2.0f * ax1 - bflo(m1);
        ay1 = 2.0f * ay1 - bfhi(m1);
        const int lr0 = wid * 16 + 2 * p, lr1 = lr0 + 1;
        lx4[(lr0 << 6) + ((lane + lr0 * 4) & 63)] = f2bf(ax0) | (f2bf(ay0) << 16);
        lx4[(lr1 << 6) + ((lane + lr1 * 4) & 63)] = f2bf(ax1) | (f2bf(ay1) << 16);
    }

    // ---- phase 2: MFMA contraction (v0 == wv0; wave reads only its LDS rows)
    const int v0 = wv0;
    const int col = lane & 15;
    const int quad = lane >> 4;
    const unsigned int* const xs[4] = {x0, x1, x2, x3};
    const int lr = wid * 16 + col;  // local LDS row for k=4 A-frag

    f32x4 acc[B][4];
#pragma unroll
    for (int b = 0; b < B; ++b)
#pragma unroll
        for (int nt = 0; nt < 4; ++nt) acc[b][nt] = (f32x4){0.f, 0.f, 0.f, 0.f};

#pragma unroll
    for (int k = 0; k < K; ++k) {
        bf16x8 a0, a1, a2, a3;
        if (k < 4) {
            const unsigned short* xk =
                reinterpret_cast<const unsigned short*>(xs[k]) + ((size_t)(v0 + col)) * C + quad * 8;
            a0 = *reinterpret_cast<const bf16x8*>(xk);
            a1 = *reinterpret_cast<const bf16x8*>(xk + 32);
            a2 = *reinterpret_cast<const bf16x8*>(xk + 64);
            a3 = *reinterpret_cast<const bf16x8*>(xk + 96);
        } else {
            uint4 u0 = *reinterpret_cast<const uint4*>(&lx4[(lr << 6) + ((0 * 16 + quad * 4 + lr * 4) & 63)]);
            uint4 u1 = *reinterpret_cast<const uint4*>(&lx4[(lr << 6) + ((1 * 16 + quad * 4 + lr * 4) & 63)]);
            uint4 u2 = *reinterpret_cast<const uint4*>(&lx4[(lr << 6) + ((2 * 16 + quad * 4 + lr * 4) & 63)]);
            uint4 u3 = *reinterpret_cast<const uint4*>(&lx4[(lr << 6) + ((3 * 16 + quad * 4 + lr * 4) & 63)]);
            a0 = *reinterpret_cast<bf16x8*>(&u0);
            a1 = *reinterpret_cast<bf16x8*>(&u1);
            a2 = *reinterpret_cast<bf16x8*>(&u2);
            a3 = *reinterpret_cast<bf16x8*>(&u3);
        }
#pragma unroll
        for (int nt = 0; nt < 4; ++nt) {
            uint4 uh = wfh[(k * 4 + nt) * 64 + lane];
            uint4 ul = wfl[(k * 4 + nt) * 64 + lane];
            bf16x8 wh = *reinterpret_cast<bf16x8*>(&uh);
            bf16x8 wl = *reinterpret_cast<bf16x8*>(&ul);
            acc[0][nt] = __builtin_amdgcn_mfma_f32_16x16x32_bf16(a0, wh, acc[0][nt], 0, 0, 0);
            acc[1][nt] = __builtin_amdgcn_mfma_f32_16x16x32_bf16(a1, wh, acc[1][nt], 0, 0, 0);
            acc[2][nt] = __builtin_amdgcn_mfma_f32_16x16x32_bf16(a2, wh, acc[2][nt], 0, 0, 0);
            acc[3][nt] = __builtin_amdgcn_mfma_f32_16x16x32_bf16(a3, wh, acc[3][nt], 0, 0, 0);
            acc[0][nt] = __builtin_amdgcn_mfma_f32_16x16x32_bf16(a0, wl, acc[0][nt], 0, 0, 0);
            acc[1][nt] = __builtin_amdgcn_mfma_f32_16x16x32_bf16(a1, wl, acc[1][nt], 0, 0, 0);
            acc[2][nt] = __builtin_amdgcn_mfma_f32_16x16x32_bf16(a2, wl, acc[2][nt], 0, 0, 0);
            acc[3][nt] = __builtin_amdgcn_mfma_f32_16x16x32_bf16(a3, wl, acc[3][nt], 0, 0, 0);
        }
    }

    float bv[4];
#pragma unroll
    for (int nt = 0; nt < 4; ++nt) bv[nt] = bias[nt * 16 + col];
#pragma unroll
    for (int b = 0; b < B; ++b)
#pragma unroll
        for (int nt = 0; nt < 4; ++nt)
#pragma unroll
            for (int r = 0; r < 4; ++r) {
                int row = quad * 4 + r;
                out[((size_t)b * V + v0 + row) * FOUT + nt * 16 + col] = acc[b][nt][r] + bv[nt];
            }
}

// ---------------------------------------------------------------------------
extern "C" void kernel_launch(void* const* d_in, const int* in_sizes, int n_in,
                              void* d_out, int out_size, void* d_ws, size_t ws_size,
                              hipStream_t stream) {
    const int* lap_rows = (const int*)d_in[0];
    const int* lap_cols = (const int*)d_in[1];
    const float* lap_vals = (const float*)d_in[2];
    const float* inputs = (const float*)d_in[3];
    const float* weight = (const float*)d_in[4];  // flat [160][64] == effective W
    const float* bias = (const float*)d_in[5];
    float* out = (float*)d_out;

    char* p = (char*)d_ws;
    auto alloc = [&](size_t bytes) {
        char* r = p;
        p += (bytes + 511) & ~(size_t)511;
        return r;
    };
    int* rowptr = (int*)alloc((size_t)(V + 1) * 4);
    int* cursor = (int*)alloc((size_t)V * 4);
    int* bsum = (int*)alloc(192 * 4);
    int* bpre = (int*)alloc(192 * 4);
    uint4* wfh = (uint4*)alloc((size_t)K * 4 * 64 * 16);
    uint4* wfl = (uint4*)alloc((size_t)K * 4 * 64 * 16);
    int2* cev = (int2*)alloc((size_t)NNZ * 8);
    unsigned int* xb0 = (unsigned int*)alloc((size_t)V * ROWU * 4);
    unsigned int* xb1 = (unsigned int*)alloc((size_t)V * ROWU * 4);
    unsigned int* xb2 = (unsigned int*)alloc((size_t)V * ROWU * 4);
    unsigned int* xb3 = (unsigned int*)alloc((size_t)V * ROWU * 4);

    const int edge_blocks = (NNZ + 255) / 256;
    const int x0_blocks = (V * 16 + 255) / 256;  // 12288
    const int mfma_blocks = V / 64;              // 3072

    // ---- CSR build ----
    zero_cursor<<<(V / 4 + 255) / 256, 256, 0, stream>>>((uint4*)cursor);
    hist_rows<<<edge_blocks, 256, 0, stream>>>(lap_rows, cursor);
    chunk_sums<<<V / 1024, 1024, 0, stream>>>(cursor, bsum);
    scan_sums<<<1, 256, 0, stream>>>(bsum, bpre, rowptr);
    scan_chunks<<<V / 1024, 1024, 0, stream>>>(cursor, bpre, rowptr, cursor);
    // windowed scatter: 4 passes over row ranges (write locality)
    for (int w = 0; w < 4; ++w) {
        scatter_edges_win<<<edge_blocks, 256, 0, stream>>>(
            lap_rows, lap_cols, lap_vals, cursor, cev, w * (V / 4), (w + 1) * (V / 4));
    }

    // ---- x0 (bf16, b-major rows) + W fragments ----
    build_x0<<<x0_blocks, 256, 0, stream>>>(inputs, (uint4*)xb0);
    build_wfrag<<<5, 256, 0, stream>>>(weight, wfh, wfl);

    // ---- Chebyshev recurrence (bf16 storage, f32 accumulate) ----
    spmm_gather<0><<<SPMM_BLOCKS, 256, 0, stream>>>(rowptr, cev, xb0, nullptr, xb1);
    spmm_gather<1><<<SPMM_BLOCKS, 256, 0, stream>>>(rowptr, cev, xb1, xb0, xb2);
    spmm_gather<1><<<SPMM_BLOCKS, 256, 0, stream>>>(rowptr, cev, xb2, xb1, xb3);

    // ---- fused: x4 in-kernel (LDS) + MFMA contraction ----
    fused_mfma<<<mfma_blocks, 256, 0, stream>>>(xb0, xb1, xb2, xb3, rowptr, cev,
                                                wfh, wfl, bias, out);
}

// Round 11
// 630.167 us; speedup vs baseline: 1.1658x; 1.1658x over previous
//
#include <hip/hip_runtime.h>

#define V 196608
#define NNZ (9 * V)
#define B 4
#define FIN 32
#define FOUT 64
#define K 5
#define C 128            // FIN*B feature columns per vertex
#define ROWU 64          // uints per bf16 row (128 feats * 2B / 4B)
#define SPMM_BLOCKS 2048 // persistent grid: 8 blocks/CU * 256 CU

typedef __attribute__((ext_vector_type(8))) short bf16x8;
typedef __attribute__((ext_vector_type(4))) float f32x4;

// ---- bf16 helpers (bit-level, RNE) ---------------------------------------
static __device__ __forceinline__ unsigned int f2bf(float f) {
    union { float f; unsigned int u; } v; v.f = f;
    return (v.u + 0x7FFFu + ((v.u >> 16) & 1u)) >> 16;
}
static __device__ __forceinline__ float bflo(unsigned int u) {
    union { unsigned int u; float f; } v; v.u = u << 16; return v.f;
}
static __device__ __forceinline__ float bfhi(unsigned int u) {
    union { unsigned int u; float f; } v; v.u = u & 0xFFFF0000u; return v.f;
}

// ---------------------------------------------------------------------------
// fast zero for cursor: V ints = 48K uint4
__global__ void zero_cursor(uint4* __restrict__ p) {
    int t = blockIdx.x * 256 + threadIdx.x;
    if (t < V / 4) p[t] = (uint4){0u, 0u, 0u, 0u};
}

// ---------------------------------------------------------------------------
// x0[v][b*32+fin] (bf16, b-major row), vectorized: thread = one uint4 (8 feats)
__global__ void build_x0(const float* __restrict__ inp, uint4* __restrict__ x0v) {
    int t = blockIdx.x * 256 + threadIdx.x;
    if (t >= V * 16) return;
    int v = t >> 4;
    int seg = t & 15;   // dwords seg*4..+3 == b*16 + q*4 + 0..3
    int b = seg >> 2;
    int q = seg & 3;
    const float4* s = reinterpret_cast<const float4*>(inp + ((size_t)b * V + v) * 32 + q * 8);
    float4 fa = s[0], fb = s[1];
    uint4 u;
    u.x = f2bf(fa.x) | (f2bf(fa.y) << 16);
    u.y = f2bf(fa.z) | (f2bf(fa.w) << 16);
    u.z = f2bf(fb.x) | (f2bf(fb.y) << 16);
    u.w = f2bf(fb.z) | (f2bf(fb.w) << 16);
    x0v[(size_t)v * 16 + seg] = u;
}

// ---------------------------------------------------------------------------
// W fragment prep: split-precision bf16 B-fragments, k-major K ordering.
__global__ void build_wfrag(const float* __restrict__ w, uint4* __restrict__ wfh,
                            uint4* __restrict__ wfl) {
    int idx = blockIdx.x * 256 + threadIdx.x;
    if (idx >= K * 4 * 64) return;
    int lane = idx & 63;
    int nt = (idx >> 6) & 3;
    int k = idx >> 8;
    int col = lane & 15;
    int quad = lane >> 4;
    int o = nt * 16 + col;
    unsigned int hh[8], ll[8];
#pragma unroll
    for (int e = 0; e < 8; ++e) {
        int fin = quad * 8 + e;
        float wv = w[(fin * 5 + k) * 64 + o];
        unsigned int hb = f2bf(wv);
        float hf = bflo(hb);
        ll[e] = f2bf(wv - hf);
        hh[e] = hb;
    }
    uint4 uh, ul;
    uh.x = hh[0] | (hh[1] << 16);
    uh.y = hh[2] | (hh[3] << 16);
    uh.z = hh[4] | (hh[5] << 16);
    uh.w = hh[6] | (hh[7] << 16);
    ul.x = ll[0] | (ll[1] << 16);
    ul.y = ll[2] | (ll[3] << 16);
    ul.z = ll[4] | (ll[5] << 16);
    ul.w = ll[6] | (ll[7] << 16);
    wfh[idx] = uh;
    wfl[idx] = ul;
}

// ---------------------------------------------------------------------------
// CSR build step 1: histogram row counts into cnt[] (pre-zeroed)
__global__ void hist_rows(const int* __restrict__ rows, int* __restrict__ cnt) {
    int e = blockIdx.x * 256 + threadIdx.x;
    if (e < NNZ) atomicAdd(&cnt[rows[e]], 1);
}

// ---------------------------------------------------------------------------
// parallel scan phase A: per-1024-chunk sums
__global__ void chunk_sums(const int* __restrict__ cnt, int* __restrict__ bsum) {
    __shared__ int ws[16];
    int tid = threadIdx.x;
    int lane = tid & 63;
    int wid = tid >> 6;
    int v = cnt[blockIdx.x * 1024 + tid];
#pragma unroll
    for (int off = 32; off >= 1; off >>= 1) v += __shfl_down(v, off, 64);
    if (lane == 0) ws[wid] = v;
    __syncthreads();
    if (tid < 16) {
        int s = ws[tid];
#pragma unroll
        for (int off = 8; off >= 1; off >>= 1) s += __shfl_down(s, off, 16);
        if (tid == 0) bsum[blockIdx.x] = s;
    }
}

// ---------------------------------------------------------------------------
// parallel scan phase B: exclusive scan of 192 chunk sums
__global__ void scan_sums(const int* __restrict__ bsum, int* __restrict__ bpre,
                          int* __restrict__ rowptr) {
    __shared__ int ws[4];
    int tid = threadIdx.x;
    int lane = tid & 63;
    int wid = tid >> 6;
    int v = (tid < 192) ? bsum[tid] : 0;
    int x = v;
#pragma unroll
    for (int off = 1; off < 64; off <<= 1) {
        int t = __shfl_up(x, off, 64);
        if (lane >= off) x += t;
    }
    if (lane == 63) ws[wid] = x;
    __syncthreads();
    if (wid == 0 && lane < 4) {
        int s = ws[lane];
        int y = s;
#pragma unroll
        for (int off = 1; off < 4; off <<= 1) {
            int t = __shfl_up(y, off, 4);
            if (lane >= off) y += t;
        }
        ws[lane] = y - s;
    }
    __syncthreads();
    int incl = x + ws[wid];
    if (tid < 192) bpre[tid] = incl - v;
    if (tid == 191) rowptr[V] = incl;
}

// ---------------------------------------------------------------------------
// parallel scan phase C: per-chunk scan + chunk prefix
__global__ void scan_chunks(const int* __restrict__ cnt, const int* __restrict__ bpre,
                            int* __restrict__ rowptr, int* __restrict__ cursor) {
    __shared__ int wsum[16];
    int tid = threadIdx.x;
    int lane = tid & 63;
    int wid = tid >> 6;
    int base = blockIdx.x * 1024;
    int v = cnt[base + tid];
    int x = v;
#pragma unroll
    for (int off = 1; off < 64; off <<= 1) {
        int t = __shfl_up(x, off, 64);
        if (lane >= off) x += t;
    }
    if (lane == 63) wsum[wid] = x;
    __syncthreads();
    if (wid == 0 && lane < 16) {
        int s = wsum[lane];
        int y = s;
#pragma unroll
        for (int off = 1; off < 16; off <<= 1) {
            int t = __shfl_up(y, off, 16);
            if (lane >= off) y += t;
        }
        wsum[lane] = y - s;
    }
    __syncthreads();
    int excl = x - v + wsum[wid] + bpre[blockIdx.x];
    rowptr[base + tid] = excl;
    cursor[base + tid] = excl;
}

// ---------------------------------------------------------------------------
// windowed CSR scatter: pass only handles rows in [lo, hi) so cev writes and
// cursor atomics concentrate in an L2-hot window (kills 64B-line write amp).
__global__ void scatter_edges_win(const int* __restrict__ rows, const int* __restrict__ cols,
                                  const float* __restrict__ vals, int* __restrict__ cursor,
                                  int2* __restrict__ cev, int lo, int hi) {
    int e = blockIdx.x * 256 + threadIdx.x;
    if (e >= NNZ) return;
    int r = rows[e];
    if (r < lo || r >= hi) return;
    int p = atomicAdd(&cursor[r], 1);
    int2 pk;
    pk.x = cols[e];
    pk.y = __float_as_int(vals[e]);
    cev[p] = pk;
}

// ---------------------------------------------------------------------------
// bf16 gather SpMM v3.1: persistent waves, 2 rows per iteration, joint 4+4
// strip-mine (8 gathers in flight), then solo 4-strips before 2/1 drains.
template <int COMBINE>
__global__ __launch_bounds__(256) void spmm_gather(
    const int* __restrict__ rowptr, const int2* __restrict__ cev,
    const unsigned int* __restrict__ x, const unsigned int* __restrict__ xm2,
    unsigned int* __restrict__ y) {
    const int lane = threadIdx.x & 63;
    const int wid0 = (blockIdx.x * 256 + threadIdx.x) >> 6;
    const int NW = SPMM_BLOCKS * 4;  // total waves
    for (int base = wid0 * 2; base < V; base += NW * 2) {
        const int r0 = base, r1 = base + 1;
        const int s0 = rowptr[r0];
        const int e0 = rowptr[r0 + 1];
        const int e1 = rowptr[r1 + 1];  // s1 == e0
        float ax0 = 0.f, ay0 = 0.f, ax1 = 0.f, ay1 = 0.f;
        int i0 = s0, i1 = e0;
        while (e0 - i0 >= 4 && e1 - i1 >= 4) {
            int2 Ea[4], Eb[4];
#pragma unroll
            for (int j = 0; j < 4; ++j) {
                Ea[j] = cev[i0 + j];
                Eb[j] = cev[i1 + j];
            }
            unsigned int Ua[4], Ub[4];
#pragma unroll
            for (int j = 0; j < 4; ++j) {
                Ua[j] = x[(size_t)Ea[j].x * ROWU + lane];
                Ub[j] = x[(size_t)Eb[j].x * ROWU + lane];
            }
#pragma unroll
            for (int j = 0; j < 4; ++j) {
                float va = __int_as_float(Ea[j].y);
                float vb = __int_as_float(Eb[j].y);
                ax0 = fmaf(va, bflo(Ua[j]), ax0);
                ay0 = fmaf(va, bfhi(Ua[j]), ay0);
                ax1 = fmaf(vb, bflo(Ub[j]), ax1);
                ay1 = fmaf(vb, bfhi(Ub[j]), ay1);
            }
            i0 += 4;
            i1 += 4;
        }
        // solo 4-strips (MLP 4) for whichever row still has >=4 edges
        while (e0 - i0 >= 4) {
            int2 Ea[4];
#pragma unroll
            for (int j = 0; j < 4; ++j) Ea[j] = cev[i0 + j];
            unsigned int Ua[4];
#pragma unroll
            for (int j = 0; j < 4; ++j) Ua[j] = x[(size_t)Ea[j].x * ROWU + lane];
#pragma unroll
            for (int j = 0; j < 4; ++j) {
                float va = __int_as_float(Ea[j].y);
                ax0 = fmaf(va, bflo(Ua[j]), ax0);
                ay0 = fmaf(va, bfhi(Ua[j]), ay0);
            }
            i0 += 4;
        }
        while (e1 - i1 >= 4) {
            int2 Eb[4];
#pragma unroll
            for (int j = 0; j < 4; ++j) Eb[j] = cev[i1 + j];
            unsigned int Ub[4];
#pragma unroll
            for (int j = 0; j < 4; ++j) Ub[j] = x[(size_t)Eb[j].x * ROWU + lane];
#pragma unroll
            for (int j = 0; j < 4; ++j) {
                float vb = __int_as_float(Eb[j].y);
                ax1 = fmaf(vb, bflo(Ub[j]), ax1);
                ay1 = fmaf(vb, bfhi(Ub[j]), ay1);
            }
            i1 += 4;
        }
        for (; i0 + 2 <= e0; i0 += 2) {
            int2 a = cev[i0], b = cev[i0 + 1];
            unsigned int u0 = x[(size_t)a.x * ROWU + lane];
            unsigned int u1 = x[(size_t)b.x * ROWU + lane];
            float v0 = __int_as_float(a.y), v1 = __int_as_float(b.y);
            ax0 = fmaf(v0, bflo(u0), ax0);
            ay0 = fmaf(v0, bfhi(u0), ay0);
            ax0 = fmaf(v1, bflo(u1), ax0);
            ay0 = fmaf(v1, bfhi(u1), ay0);
        }
        for (; i0 < e0; ++i0) {
            int2 a = cev[i0];
            unsigned int u = x[(size_t)a.x * ROWU + lane];
            float v = __int_as_float(a.y);
            ax0 = fmaf(v, bflo(u), ax0);
            ay0 = fmaf(v, bfhi(u), ay0);
        }
        for (; i1 + 2 <= e1; i1 += 2) {
            int2 a = cev[i1], b = cev[i1 + 1];
            unsigned int u0 = x[(size_t)a.x * ROWU + lane];
            unsigned int u1 = x[(size_t)b.x * ROWU + lane];
            float v0 = __int_as_float(a.y), v1 = __int_as_float(b.y);
            ax1 = fmaf(v0, bflo(u0), ax1);
            ay1 = fmaf(v0, bfhi(u0), ay1);
            ax1 = fmaf(v1, bflo(u1), ax1);
            ay1 = fmaf(v1, bfhi(u1), ay1);
        }
        for (; i1 < e1; ++i1) {
            int2 a = cev[i1];
            unsigned int u = x[(size_t)a.x * ROWU + lane];
            float v = __int_as_float(a.y);
            ax1 = fmaf(v, bflo(u), ax1);
            ay1 = fmaf(v, bfhi(u), ay1);
        }
        if (COMBINE) {
            unsigned int m0 = xm2[(size_t)r0 * ROWU + lane];
            unsigned int m1 = xm2[(size_t)r1 * ROWU + lane];
            ax0 = 2.0f * ax0 - bflo(m0);
            ay0 = 2.0f * ay0 - bfhi(m0);
            ax1 = 2.0f * ax1 - bflo(m1);
            ay1 = 2.0f * ay1 - bfhi(m1);
        }
        y[(size_t)r0 * ROWU + lane] = f2bf(ax0) | (f2bf(ay0) << 16);
        y[(size_t)r1 * ROWU + lane] = f2bf(ax1) | (f2bf(ay1) << 16);
    }
}

// ---------------------------------------------------------------------------
// MFMA fused output contraction (standalone, round-8 proven).
// Wave = 16 vertices x 64 outs x 4 batches.
// A-frag: lane l holds x[v0+(l&15)][b*32 + (l>>4)*8 .. +8]  (one 16B load)
// C/D:    col=lane&15, row=(lane>>4)*4+reg   [m89-verified mapping]
__global__ __launch_bounds__(256) void fused_mfma(
    const unsigned short* __restrict__ x0, const unsigned short* __restrict__ x1,
    const unsigned short* __restrict__ x2, const unsigned short* __restrict__ x3,
    const unsigned short* __restrict__ x4, const uint4* __restrict__ wfh,
    const uint4* __restrict__ wfl, const float* __restrict__ bias,
    float* __restrict__ out) {
    const int tid = threadIdx.x;
    const int lane = tid & 63;
    const int g = (blockIdx.x * 256 + tid) >> 6;
    const int v0 = g << 4;
    const int col = lane & 15;
    const int quad = lane >> 4;
    const unsigned short* const xs[K] = {x0, x1, x2, x3, x4};

    f32x4 acc[B][4];
#pragma unroll
    for (int b = 0; b < B; ++b)
#pragma unroll
        for (int nt = 0; nt < 4; ++nt) acc[b][nt] = (f32x4){0.f, 0.f, 0.f, 0.f};

#pragma unroll
    for (int k = 0; k < K; ++k) {
        const unsigned short* xk = xs[k] + ((size_t)(v0 + col)) * C + quad * 8;
        bf16x8 a0 = *reinterpret_cast<const bf16x8*>(xk);
        bf16x8 a1 = *reinterpret_cast<const bf16x8*>(xk + 32);
        bf16x8 a2 = *reinterpret_cast<const bf16x8*>(xk + 64);
        bf16x8 a3 = *reinterpret_cast<const bf16x8*>(xk + 96);
#pragma unroll
        for (int nt = 0; nt < 4; ++nt) {
            uint4 uh = wfh[(k * 4 + nt) * 64 + lane];
            uint4 ul = wfl[(k * 4 + nt) * 64 + lane];
            bf16x8 wh = *reinterpret_cast<bf16x8*>(&uh);
            bf16x8 wl = *reinterpret_cast<bf16x8*>(&ul);
            acc[0][nt] = __builtin_amdgcn_mfma_f32_16x16x32_bf16(a0, wh, acc[0][nt], 0, 0, 0);
            acc[1][nt] = __builtin_amdgcn_mfma_f32_16x16x32_bf16(a1, wh, acc[1][nt], 0, 0, 0);
            acc[2][nt] = __builtin_amdgcn_mfma_f32_16x16x32_bf16(a2, wh, acc[2][nt], 0, 0, 0);
            acc[3][nt] = __builtin_amdgcn_mfma_f32_16x16x32_bf16(a3, wh, acc[3][nt], 0, 0, 0);
            acc[0][nt] = __builtin_amdgcn_mfma_f32_16x16x32_bf16(a0, wl, acc[0][nt], 0, 0, 0);
            acc[1][nt] = __builtin_amdgcn_mfma_f32_16x16x32_bf16(a1, wl, acc[1][nt], 0, 0, 0);
            acc[2][nt] = __builtin_amdgcn_mfma_f32_16x16x32_bf16(a2, wl, acc[2][nt], 0, 0, 0);
            acc[3][nt] = __builtin_amdgcn_mfma_f32_16x16x32_bf16(a3, wl, acc[3][nt], 0, 0, 0);
        }
    }

    float bv[4];
#pragma unroll
    for (int nt = 0; nt < 4; ++nt) bv[nt] = bias[nt * 16 + col];
#pragma unroll
    for (int b = 0; b < B; ++b)
#pragma unroll
        for (int nt = 0; nt < 4; ++nt)
#pragma unroll
            for (int r = 0; r < 4; ++r) {
                int row = quad * 4 + r;
                out[((size_t)b * V + v0 + row) * FOUT + nt * 16 + col] = acc[b][nt][r] + bv[nt];
            }
}

// ---------------------------------------------------------------------------
extern "C" void kernel_launch(void* const* d_in, const int* in_sizes, int n_in,
                              void* d_out, int out_size, void* d_ws, size_t ws_size,
                              hipStream_t stream) {
    const int* lap_rows = (const int*)d_in[0];
    const int* lap_cols = (const int*)d_in[1];
    const float* lap_vals = (const float*)d_in[2];
    const float* inputs = (const float*)d_in[3];
    const float* weight = (const float*)d_in[4];  // flat [160][64] == effective W
    const float* bias = (const float*)d_in[5];
    float* out = (float*)d_out;

    char* p = (char*)d_ws;
    auto alloc = [&](size_t bytes) {
        char* r = p;
        p += (bytes + 511) & ~(size_t)511;
        return r;
    };
    int* rowptr = (int*)alloc((size_t)(V + 1) * 4);
    int* cursor = (int*)alloc((size_t)V * 4);
    int* bsum = (int*)alloc(192 * 4);
    int* bpre = (int*)alloc(192 * 4);
    uint4* wfh = (uint4*)alloc((size_t)K * 4 * 64 * 16);
    uint4* wfl = (uint4*)alloc((size_t)K * 4 * 64 * 16);
    int2* cev = (int2*)alloc((size_t)NNZ * 8);
    unsigned int* xb0 = (unsigned int*)alloc((size_t)V * ROWU * 4);
    unsigned int* xb1 = (unsigned int*)alloc((size_t)V * ROWU * 4);
    unsigned int* xb2 = (unsigned int*)alloc((size_t)V * ROWU * 4);
    unsigned int* xb3 = (unsigned int*)alloc((size_t)V * ROWU * 4);
    unsigned int* xb4 = (unsigned int*)alloc((size_t)V * ROWU * 4);

    const int edge_blocks = (NNZ + 255) / 256;
    const int x0_blocks = (V * 16 + 255) / 256;  // 12288
    const int mfma_blocks = (V / 16) * 64 / 256; // 3072

    // ---- CSR build ----
    zero_cursor<<<(V / 4 + 255) / 256, 256, 0, stream>>>((uint4*)cursor);
    hist_rows<<<edge_blocks, 256, 0, stream>>>(lap_rows, cursor);
    chunk_sums<<<V / 1024, 1024, 0, stream>>>(cursor, bsum);
    scan_sums<<<1, 256, 0, stream>>>(bsum, bpre, rowptr);
    scan_chunks<<<V / 1024, 1024, 0, stream>>>(cursor, bpre, rowptr, cursor);
    // windowed scatter: 4 passes over row ranges (write locality)
    for (int w = 0; w < 4; ++w) {
        scatter_edges_win<<<edge_blocks, 256, 0, stream>>>(
            lap_rows, lap_cols, lap_vals, cursor, cev, w * (V / 4), (w + 1) * (V / 4));
    }

    // ---- x0 (bf16, b-major rows) + W fragments ----
    build_x0<<<x0_blocks, 256, 0, stream>>>(inputs, (uint4*)xb0);
    build_wfrag<<<5, 256, 0, stream>>>(weight, wfh, wfl);

    // ---- Chebyshev recurrence (bf16 storage, f32 accumulate) ----
    spmm_gather<0><<<SPMM_BLOCKS, 256, 0, stream>>>(rowptr, cev, xb0, nullptr, xb1);
    spmm_gather<1><<<SPMM_BLOCKS, 256, 0, stream>>>(rowptr, cev, xb1, xb0, xb2);
    spmm_gather<1><<<SPMM_BLOCKS, 256, 0, stream>>>(rowptr, cev, xb2, xb1, xb3);
    spmm_gather<1><<<SPMM_BLOCKS, 256, 0, stream>>>(rowptr, cev, xb3, xb2, xb4);

    // ---- fused MFMA output contraction ----
    fused_mfma<<<mfma_blocks, 256, 0, stream>>>(
        (const unsigned short*)xb0, (const unsigned short*)xb1, (const unsigned short*)xb2,
        (const unsigned short*)xb3, (const unsigned short*)xb4, wfh, wfl, bias, out);
}

// Round 12
// 628.654 us; speedup vs baseline: 1.1686x; 1.0024x over previous
//
#include <hip/hip_runtime.h>

#define V 196608
#define NNZ (9 * V)
#define B 4
#define FIN 32
#define FOUT 64
#define K 5
#define C 128            // FIN*B feature columns per vertex
#define ROWU 64          // uints per bf16 row (128 feats * 2B / 4B)
#define SPMM_BLOCKS 2048 // persistent grid: 8 blocks/CU * 256 CU
#define NSLICE 864       // scatter: edge slices; NNZ = 864 * 2048 exactly
#define EDGES_PER_SLICE 2048

typedef __attribute__((ext_vector_type(8))) short bf16x8;
typedef __attribute__((ext_vector_type(4))) float f32x4;

// ---- bf16 helpers (bit-level, RNE) ---------------------------------------
static __device__ __forceinline__ unsigned int f2bf(float f) {
    union { float f; unsigned int u; } v; v.f = f;
    return (v.u + 0x7FFFu + ((v.u >> 16) & 1u)) >> 16;
}
static __device__ __forceinline__ float bflo(unsigned int u) {
    union { unsigned int u; float f; } v; v.u = u << 16; return v.f;
}
static __device__ __forceinline__ float bfhi(unsigned int u) {
    union { unsigned int u; float f; } v; v.u = u & 0xFFFF0000u; return v.f;
}

// ---------------------------------------------------------------------------
// fast zero for cnt: V ints = 48K uint4
__global__ void zero_cursor(uint4* __restrict__ p) {
    int t = blockIdx.x * 256 + threadIdx.x;
    if (t < V / 4) p[t] = (uint4){0u, 0u, 0u, 0u};
}

// ---------------------------------------------------------------------------
// x0[v][b*32+fin] (bf16, b-major row), vectorized: thread = one uint4 (8 feats)
__global__ void build_x0(const float* __restrict__ inp, uint4* __restrict__ x0v) {
    int t = blockIdx.x * 256 + threadIdx.x;
    if (t >= V * 16) return;
    int v = t >> 4;
    int seg = t & 15;   // dwords seg*4..+3 == b*16 + q*4 + 0..3
    int b = seg >> 2;
    int q = seg & 3;
    const float4* s = reinterpret_cast<const float4*>(inp + ((size_t)b * V + v) * 32 + q * 8);
    float4 fa = s[0], fb = s[1];
    uint4 u;
    u.x = f2bf(fa.x) | (f2bf(fa.y) << 16);
    u.y = f2bf(fa.z) | (f2bf(fa.w) << 16);
    u.z = f2bf(fb.x) | (f2bf(fb.y) << 16);
    u.w = f2bf(fb.z) | (f2bf(fb.w) << 16);
    x0v[(size_t)v * 16 + seg] = u;
}

// ---------------------------------------------------------------------------
// W fragment prep: split-precision bf16 B-fragments, k-major K ordering.
__global__ void build_wfrag(const float* __restrict__ w, uint4* __restrict__ wfh,
                            uint4* __restrict__ wfl) {
    int idx = blockIdx.x * 256 + threadIdx.x;
    if (idx >= K * 4 * 64) return;
    int lane = idx & 63;
    int nt = (idx >> 6) & 3;
    int k = idx >> 8;
    int col = lane & 15;
    int quad = lane >> 4;
    int o = nt * 16 + col;
    unsigned int hh[8], ll[8];
#pragma unroll
    for (int e = 0; e < 8; ++e) {
        int fin = quad * 8 + e;
        float wv = w[(fin * 5 + k) * 64 + o];
        unsigned int hb = f2bf(wv);
        float hf = bflo(hb);
        ll[e] = f2bf(wv - hf);
        hh[e] = hb;
    }
    uint4 uh, ul;
    uh.x = hh[0] | (hh[1] << 16);
    uh.y = hh[2] | (hh[3] << 16);
    uh.z = hh[4] | (hh[5] << 16);
    uh.w = hh[6] | (hh[7] << 16);
    ul.x = ll[0] | (ll[1] << 16);
    ul.y = ll[2] | (ll[3] << 16);
    ul.z = ll[4] | (ll[5] << 16);
    ul.w = ll[6] | (ll[7] << 16);
    wfh[idx] = uh;
    wfl[idx] = ul;
}

// ---------------------------------------------------------------------------
// CSR build step 1: histogram + per-edge rank (rank[e] = old count of row)
__global__ void hist_rank(const int* __restrict__ rows, int* __restrict__ cnt,
                          int* __restrict__ rank) {
    int e = blockIdx.x * 256 + threadIdx.x;
    if (e < NNZ) rank[e] = atomicAdd(&cnt[rows[e]], 1);
}

// ---------------------------------------------------------------------------
// parallel scan phase A: per-1024-chunk sums
__global__ void chunk_sums(const int* __restrict__ cnt, int* __restrict__ bsum) {
    __shared__ int ws[16];
    int tid = threadIdx.x;
    int lane = tid & 63;
    int wid = tid >> 6;
    int v = cnt[blockIdx.x * 1024 + tid];
#pragma unroll
    for (int off = 32; off >= 1; off >>= 1) v += __shfl_down(v, off, 64);
    if (lane == 0) ws[wid] = v;
    __syncthreads();
    if (tid < 16) {
        int s = ws[tid];
#pragma unroll
        for (int off = 8; off >= 1; off >>= 1) s += __shfl_down(s, off, 16);
        if (tid == 0) bsum[blockIdx.x] = s;
    }
}

// ---------------------------------------------------------------------------
// parallel scan phase B: exclusive scan of 192 chunk sums
__global__ void scan_sums(const int* __restrict__ bsum, int* __restrict__ bpre,
                          int* __restrict__ rowptr) {
    __shared__ int ws[4];
    int tid = threadIdx.x;
    int lane = tid & 63;
    int wid = tid >> 6;
    int v = (tid < 192) ? bsum[tid] : 0;
    int x = v;
#pragma unroll
    for (int off = 1; off < 64; off <<= 1) {
        int t = __shfl_up(x, off, 64);
        if (lane >= off) x += t;
    }
    if (lane == 63) ws[wid] = x;
    __syncthreads();
    if (wid == 0 && lane < 4) {
        int s = ws[lane];
        int y = s;
#pragma unroll
        for (int off = 1; off < 4; off <<= 1) {
            int t = __shfl_up(y, off, 4);
            if (lane >= off) y += t;
        }
        ws[lane] = y - s;
    }
    __syncthreads();
    int incl = x + ws[wid];
    if (tid < 192) bpre[tid] = incl - v;
    if (tid == 191) rowptr[V] = incl;
}

// ---------------------------------------------------------------------------
// parallel scan phase C: per-chunk scan + chunk prefix -> rowptr
__global__ void scan_chunks(const int* __restrict__ cnt, const int* __restrict__ bpre,
                            int* __restrict__ rowptr) {
    __shared__ int wsum[16];
    int tid = threadIdx.x;
    int lane = tid & 63;
    int wid = tid >> 6;
    int base = blockIdx.x * 1024;
    int v = cnt[base + tid];
    int x = v;
#pragma unroll
    for (int off = 1; off < 64; off <<= 1) {
        int t = __shfl_up(x, off, 64);
        if (lane >= off) x += t;
    }
    if (lane == 63) wsum[wid] = x;
    __syncthreads();
    if (wid == 0 && lane < 16) {
        int s = wsum[lane];
        int y = s;
#pragma unroll
        for (int off = 1; off < 16; off <<= 1) {
            int t = __shfl_up(y, off, 16);
            if (lane >= off) y += t;
        }
        wsum[lane] = y - s;
    }
    __syncthreads();
    int excl = x - v + wsum[wid] + bpre[blockIdx.x];
    rowptr[base + tid] = excl;
}

// ---------------------------------------------------------------------------
// XCD-partitioned rank scatter: block b handles edge slice b>>3, writes only
// positions in window (b&7) of cev. blockIdx%8 round-robins XCDs, so each
// 64B cev line is dirtied by ONE XCD's L2 -> writes coalesce (no cross-XCD
// partial-line bounce). No atomics; p = rowptr[row] + rank is exact.
__global__ void scatter_rank(const int* __restrict__ rows, const int* __restrict__ cols,
                             const float* __restrict__ vals, const int* __restrict__ rowptr,
                             const int* __restrict__ rank, int2* __restrict__ cev) {
    const int slice = blockIdx.x >> 3;
    const int w = blockIdx.x & 7;
    const int lo = w * (NNZ / 8);
    const int hi = lo + (NNZ / 8);
    const int base = slice * EDGES_PER_SLICE;
#pragma unroll 2
    for (int i = threadIdx.x; i < EDGES_PER_SLICE; i += 256) {
        int e = base + i;
        int p = rowptr[rows[e]] + rank[e];
        if (p >= lo && p < hi) {
            int2 pk;
            pk.x = cols[e];
            pk.y = __float_as_int(vals[e]);
            cev[p] = pk;
        }
    }
}

// ---------------------------------------------------------------------------
// bf16 gather SpMM v3.1: persistent waves, 2 rows per iteration, joint 4+4
// strip-mine (8 gathers in flight), then solo 4-strips before 2/1 drains.
template <int COMBINE>
__global__ __launch_bounds__(256) void spmm_gather(
    const int* __restrict__ rowptr, const int2* __restrict__ cev,
    const unsigned int* __restrict__ x, const unsigned int* __restrict__ xm2,
    unsigned int* __restrict__ y) {
    const int lane = threadIdx.x & 63;
    const int wid0 = (blockIdx.x * 256 + threadIdx.x) >> 6;
    const int NW = SPMM_BLOCKS * 4;  // total waves
    for (int base = wid0 * 2; base < V; base += NW * 2) {
        const int r0 = base, r1 = base + 1;
        const int s0 = rowptr[r0];
        const int e0 = rowptr[r0 + 1];
        const int e1 = rowptr[r1 + 1];  // s1 == e0
        float ax0 = 0.f, ay0 = 0.f, ax1 = 0.f, ay1 = 0.f;
        int i0 = s0, i1 = e0;
        while (e0 - i0 >= 4 && e1 - i1 >= 4) {
            int2 Ea[4], Eb[4];
#pragma unroll
            for (int j = 0; j < 4; ++j) {
                Ea[j] = cev[i0 + j];
                Eb[j] = cev[i1 + j];
            }
            unsigned int Ua[4], Ub[4];
#pragma unroll
            for (int j = 0; j < 4; ++j) {
                Ua[j] = x[(size_t)Ea[j].x * ROWU + lane];
                Ub[j] = x[(size_t)Eb[j].x * ROWU + lane];
            }
#pragma unroll
            for (int j = 0; j < 4; ++j) {
                float va = __int_as_float(Ea[j].y);
                float vb = __int_as_float(Eb[j].y);
                ax0 = fmaf(va, bflo(Ua[j]), ax0);
                ay0 = fmaf(va, bfhi(Ua[j]), ay0);
                ax1 = fmaf(vb, bflo(Ub[j]), ax1);
                ay1 = fmaf(vb, bfhi(Ub[j]), ay1);
            }
            i0 += 4;
            i1 += 4;
        }
        while (e0 - i0 >= 4) {
            int2 Ea[4];
#pragma unroll
            for (int j = 0; j < 4; ++j) Ea[j] = cev[i0 + j];
            unsigned int Ua[4];
#pragma unroll
            for (int j = 0; j < 4; ++j) Ua[j] = x[(size_t)Ea[j].x * ROWU + lane];
#pragma unroll
            for (int j = 0; j < 4; ++j) {
                float va = __int_as_float(Ea[j].y);
                ax0 = fmaf(va, bflo(Ua[j]), ax0);
                ay0 = fmaf(va, bfhi(Ua[j]), ay0);
            }
            i0 += 4;
        }
        while (e1 - i1 >= 4) {
            int2 Eb[4];
#pragma unroll
            for (int j = 0; j < 4; ++j) Eb[j] = cev[i1 + j];
            unsigned int Ub[4];
#pragma unroll
            for (int j = 0; j < 4; ++j) Ub[j] = x[(size_t)Eb[j].x * ROWU + lane];
#pragma unroll
            for (int j = 0; j < 4; ++j) {
                float vb = __int_as_float(Eb[j].y);
                ax1 = fmaf(vb, bflo(Ub[j]), ax1);
                ay1 = fmaf(vb, bfhi(Ub[j]), ay1);
            }
            i1 += 4;
        }
        for (; i0 + 2 <= e0; i0 += 2) {
            int2 a = cev[i0], b = cev[i0 + 1];
            unsigned int u0 = x[(size_t)a.x * ROWU + lane];
            unsigned int u1 = x[(size_t)b.x * ROWU + lane];
            float v0 = __int_as_float(a.y), v1 = __int_as_float(b.y);
            ax0 = fmaf(v0, bflo(u0), ax0);
            ay0 = fmaf(v0, bfhi(u0), ay0);
            ax0 = fmaf(v1, bflo(u1), ax0);
            ay0 = fmaf(v1, bfhi(u1), ay0);
        }
        for (; i0 < e0; ++i0) {
            int2 a = cev[i0];
            unsigned int u = x[(size_t)a.x * ROWU + lane];
            float v = __int_as_float(a.y);
            ax0 = fmaf(v, bflo(u), ax0);
            ay0 = fmaf(v, bfhi(u), ay0);
        }
        for (; i1 + 2 <= e1; i1 += 2) {
            int2 a = cev[i1], b = cev[i1 + 1];
            unsigned int u0 = x[(size_t)a.x * ROWU + lane];
            unsigned int u1 = x[(size_t)b.x * ROWU + lane];
            float v0 = __int_as_float(a.y), v1 = __int_as_float(b.y);
            ax1 = fmaf(v0, bflo(u0), ax1);
            ay1 = fmaf(v0, bfhi(u0), ay1);
            ax1 = fmaf(v1, bflo(u1), ax1);
            ay1 = fmaf(v1, bfhi(u1), ay1);
        }
        for (; i1 < e1; ++i1) {
            int2 a = cev[i1];
            unsigned int u = x[(size_t)a.x * ROWU + lane];
            float v = __int_as_float(a.y);
            ax1 = fmaf(v, bflo(u), ax1);
            ay1 = fmaf(v, bfhi(u), ay1);
        }
        if (COMBINE) {
            unsigned int m0 = xm2[(size_t)r0 * ROWU + lane];
            unsigned int m1 = xm2[(size_t)r1 * ROWU + lane];
            ax0 = 2.0f * ax0 - bflo(m0);
            ay0 = 2.0f * ay0 - bfhi(m0);
            ax1 = 2.0f * ax1 - bflo(m1);
            ay1 = 2.0f * ay1 - bfhi(m1);
        }
        y[(size_t)r0 * ROWU + lane] = f2bf(ax0) | (f2bf(ay0) << 16);
        y[(size_t)r1 * ROWU + lane] = f2bf(ax1) | (f2bf(ay1) << 16);
    }
}

// ---------------------------------------------------------------------------
// MFMA fused output contraction. Wave = 16 vertices x 64 outs x 4 batches.
// A-frag: lane l holds x[v0+(l&15)][b*32 + (l>>4)*8 .. +8]  (one 16B load)
// C/D:    col=lane&15, row=(lane>>4)*4+reg   [m89-verified mapping]
__global__ __launch_bounds__(256) void fused_mfma(
    const unsigned short* __restrict__ x0, const unsigned short* __restrict__ x1,
    const unsigned short* __restrict__ x2, const unsigned short* __restrict__ x3,
    const unsigned short* __restrict__ x4, const uint4* __restrict__ wfh,
    const uint4* __restrict__ wfl, const float* __restrict__ bias,
    float* __restrict__ out) {
    const int tid = threadIdx.x;
    const int lane = tid & 63;
    const int g = (blockIdx.x * 256 + tid) >> 6;
    const int v0 = g << 4;
    const int col = lane & 15;
    const int quad = lane >> 4;
    const unsigned short* const xs[K] = {x0, x1, x2, x3, x4};

    f32x4 acc[B][4];
#pragma unroll
    for (int b = 0; b < B; ++b)
#pragma unroll
        for (int nt = 0; nt < 4; ++nt) acc[b][nt] = (f32x4){0.f, 0.f, 0.f, 0.f};

#pragma unroll
    for (int k = 0; k < K; ++k) {
        const unsigned short* xk = xs[k] + ((size_t)(v0 + col)) * C + quad * 8;
        bf16x8 a0 = *reinterpret_cast<const bf16x8*>(xk);
        bf16x8 a1 = *reinterpret_cast<const bf16x8*>(xk + 32);
        bf16x8 a2 = *reinterpret_cast<const bf16x8*>(xk + 64);
        bf16x8 a3 = *reinterpret_cast<const bf16x8*>(xk + 96);
#pragma unroll
        for (int nt = 0; nt < 4; ++nt) {
            uint4 uh = wfh[(k * 4 + nt) * 64 + lane];
            uint4 ul = wfl[(k * 4 + nt) * 64 + lane];
            bf16x8 wh = *reinterpret_cast<bf16x8*>(&uh);
            bf16x8 wl = *reinterpret_cast<bf16x8*>(&ul);
            acc[0][nt] = __builtin_amdgcn_mfma_f32_16x16x32_bf16(a0, wh, acc[0][nt], 0, 0, 0);
            acc[1][nt] = __builtin_amdgcn_mfma_f32_16x16x32_bf16(a1, wh, acc[1][nt], 0, 0, 0);
            acc[2][nt] = __builtin_amdgcn_mfma_f32_16x16x32_bf16(a2, wh, acc[2][nt], 0, 0, 0);
            acc[3][nt] = __builtin_amdgcn_mfma_f32_16x16x32_bf16(a3, wh, acc[3][nt], 0, 0, 0);
            acc[0][nt] = __builtin_amdgcn_mfma_f32_16x16x32_bf16(a0, wl, acc[0][nt], 0, 0, 0);
            acc[1][nt] = __builtin_amdgcn_mfma_f32_16x16x32_bf16(a1, wl, acc[1][nt], 0, 0, 0);
            acc[2][nt] = __builtin_amdgcn_mfma_f32_16x16x32_bf16(a2, wl, acc[2][nt], 0, 0, 0);
            acc[3][nt] = __builtin_amdgcn_mfma_f32_16x16x32_bf16(a3, wl, acc[3][nt], 0, 0, 0);
        }
    }

    float bv[4];
#pragma unroll
    for (int nt = 0; nt < 4; ++nt) bv[nt] = bias[nt * 16 + col];
#pragma unroll
    for (int b = 0; b < B; ++b)
#pragma unroll
        for (int nt = 0; nt < 4; ++nt)
#pragma unroll
            for (int r = 0; r < 4; ++r) {
                int row = quad * 4 + r;
                out[((size_t)b * V + v0 + row) * FOUT + nt * 16 + col] = acc[b][nt][r] + bv[nt];
            }
}

// ---------------------------------------------------------------------------
extern "C" void kernel_launch(void* const* d_in, const int* in_sizes, int n_in,
                              void* d_out, int out_size, void* d_ws, size_t ws_size,
                              hipStream_t stream) {
    const int* lap_rows = (const int*)d_in[0];
    const int* lap_cols = (const int*)d_in[1];
    const float* lap_vals = (const float*)d_in[2];
    const float* inputs = (const float*)d_in[3];
    const float* weight = (const float*)d_in[4];  // flat [160][64] == effective W
    const float* bias = (const float*)d_in[5];
    float* out = (float*)d_out;

    char* p = (char*)d_ws;
    auto alloc = [&](size_t bytes) {
        char* r = p;
        p += (bytes + 511) & ~(size_t)511;
        return r;
    };
    int* rowptr = (int*)alloc((size_t)(V + 1) * 4);
    int* cnt = (int*)alloc((size_t)V * 4);
    int* bsum = (int*)alloc(192 * 4);
    int* bpre = (int*)alloc(192 * 4);
    int* rank = (int*)alloc((size_t)NNZ * 4);
    uint4* wfh = (uint4*)alloc((size_t)K * 4 * 64 * 16);
    uint4* wfl = (uint4*)alloc((size_t)K * 4 * 64 * 16);
    int2* cev = (int2*)alloc((size_t)NNZ * 8);
    unsigned int* xb0 = (unsigned int*)alloc((size_t)V * ROWU * 4);
    unsigned int* xb1 = (unsigned int*)alloc((size_t)V * ROWU * 4);
    unsigned int* xb2 = (unsigned int*)alloc((size_t)V * ROWU * 4);
    unsigned int* xb3 = (unsigned int*)alloc((size_t)V * ROWU * 4);
    unsigned int* xb4 = (unsigned int*)alloc((size_t)V * ROWU * 4);

    const int edge_blocks = (NNZ + 255) / 256;
    const int x0_blocks = (V * 16 + 255) / 256;  // 12288
    const int mfma_blocks = (V / 16) * 64 / 256; // 3072

    // ---- CSR build (rank-based, no scatter atomics) ----
    zero_cursor<<<(V / 4 + 255) / 256, 256, 0, stream>>>((uint4*)cnt);
    hist_rank<<<edge_blocks, 256, 0, stream>>>(lap_rows, cnt, rank);
    chunk_sums<<<V / 1024, 1024, 0, stream>>>(cnt, bsum);
    scan_sums<<<1, 256, 0, stream>>>(bsum, bpre, rowptr);
    scan_chunks<<<V / 1024, 1024, 0, stream>>>(cnt, bpre, rowptr);
    scatter_rank<<<NSLICE * 8, 256, 0, stream>>>(lap_rows, lap_cols, lap_vals, rowptr,
                                                 rank, cev);

    // ---- x0 (bf16, b-major rows) + W fragments ----
    build_x0<<<x0_blocks, 256, 0, stream>>>(inputs, (uint4*)xb0);
    build_wfrag<<<5, 256, 0, stream>>>(weight, wfh, wfl);

    // ---- Chebyshev recurrence (bf16 storage, f32 accumulate) ----
    spmm_gather<0><<<SPMM_BLOCKS, 256, 0, stream>>>(rowptr, cev, xb0, nullptr, xb1);
    spmm_gather<1><<<SPMM_BLOCKS, 256, 0, stream>>>(rowptr, cev, xb1, xb0, xb2);
    spmm_gather<1><<<SPMM_BLOCKS, 256, 0, stream>>>(rowptr, cev, xb2, xb1, xb3);
    spmm_gather<1><<<SPMM_BLOCKS, 256, 0, stream>>>(rowptr, cev, xb3, xb2, xb4);

    // ---- fused MFMA output contraction ----
    fused_mfma<<<mfma_blocks, 256, 0, stream>>>(
        (const unsigned short*)xb0, (const unsigned short*)xb1, (const unsigned short*)xb2,
        (const unsigned short*)xb3, (const unsigned short*)xb4, wfh, wfl, bias, out);
}

// Round 13
// 623.636 us; speedup vs baseline: 1.1780x; 1.0080x over previous
//
#include <hip/hip_runtime.h>

#define V 196608
#define NNZ (9 * V)
#define B 4
#define FIN 32
#define FOUT 64
#define K 5
#define C 128            // FIN*B feature columns per vertex
#define ROWU 64          // uints per bf16 row (128 feats * 2B / 4B)
#define SPMM_BLOCKS 2048 // persistent grid: 8 blocks/CU * 256 CU
#define NSLICE 864       // scatter: edge slices; NNZ = 864 * 2048 exactly
#define EDGES_PER_SLICE 2048
#define HIST_BLOCKS (NNZ / 256)    // 6912
#define X0_BLOCKS (V * 16 / 256)   // 12288
#define WFRAG_BLOCKS 5

typedef __attribute__((ext_vector_type(8))) short bf16x8;
typedef __attribute__((ext_vector_type(4))) float f32x4;

// ---- bf16 helpers (bit-level, RNE) ---------------------------------------
static __device__ __forceinline__ unsigned int f2bf(float f) {
    union { float f; unsigned int u; } v; v.f = f;
    return (v.u + 0x7FFFu + ((v.u >> 16) & 1u)) >> 16;
}
static __device__ __forceinline__ float bflo(unsigned int u) {
    union { unsigned int u; float f; } v; v.u = u << 16; return v.f;
}
static __device__ __forceinline__ float bfhi(unsigned int u) {
    union { unsigned int u; float f; } v; v.u = u & 0xFFFF0000u; return v.f;
}

// ---------------------------------------------------------------------------
// fast zero for cnt: V ints = 48K uint4
__global__ void zero_cursor(uint4* __restrict__ p) {
    int t = blockIdx.x * 256 + threadIdx.x;
    if (t < V / 4) p[t] = (uint4){0u, 0u, 0u, 0u};
}

// ---------------------------------------------------------------------------
// FUSED prep: [0, HIST) = histogram+rank; [HIST, HIST+X0) = x0 transpose;
// tail = W fragment build. All three mutually independent -> one dispatch,
// latency-bound hist overlaps BW-bound x0.
__global__ void prep_fused(const int* __restrict__ rows, int* __restrict__ cnt,
                           int* __restrict__ rank, const float* __restrict__ inp,
                           uint4* __restrict__ x0v, const float* __restrict__ w,
                           uint4* __restrict__ wfh, uint4* __restrict__ wfl) {
    const int blk = blockIdx.x;
    if (blk < HIST_BLOCKS) {
        // ---- histogram + per-edge rank (NNZ == HIST_BLOCKS*256 exactly) ----
        int e = blk * 256 + threadIdx.x;
        rank[e] = atomicAdd(&cnt[rows[e]], 1);
    } else if (blk < HIST_BLOCKS + X0_BLOCKS) {
        // ---- x0[v][b*32+fin] bf16 b-major; thread = one uint4 (8 feats) ----
        int t = (blk - HIST_BLOCKS) * 256 + threadIdx.x;  // < V*16 exactly
        int v = t >> 4;
        int seg = t & 15;
        int b = seg >> 2;
        int q = seg & 3;
        const float4* s =
            reinterpret_cast<const float4*>(inp + ((size_t)b * V + v) * 32 + q * 8);
        float4 fa = s[0], fb = s[1];
        uint4 u;
        u.x = f2bf(fa.x) | (f2bf(fa.y) << 16);
        u.y = f2bf(fa.z) | (f2bf(fa.w) << 16);
        u.z = f2bf(fb.x) | (f2bf(fb.y) << 16);
        u.w = f2bf(fb.z) | (f2bf(fb.w) << 16);
        x0v[(size_t)v * 16 + seg] = u;
    } else {
        // ---- W fragments: split-precision bf16 B-frags, k-major ----
        int idx = (blk - HIST_BLOCKS - X0_BLOCKS) * 256 + threadIdx.x;
        if (idx >= K * 4 * 64) return;
        int lane = idx & 63;
        int nt = (idx >> 6) & 3;
        int k = idx >> 8;
        int col = lane & 15;
        int quad = lane >> 4;
        int o = nt * 16 + col;
        unsigned int hh[8], ll[8];
#pragma unroll
        for (int e = 0; e < 8; ++e) {
            int fin = quad * 8 + e;
            float wv = w[(fin * 5 + k) * 64 + o];
            unsigned int hb = f2bf(wv);
            float hf = bflo(hb);
            ll[e] = f2bf(wv - hf);
            hh[e] = hb;
        }
        uint4 uh, ul;
        uh.x = hh[0] | (hh[1] << 16);
        uh.y = hh[2] | (hh[3] << 16);
        uh.z = hh[4] | (hh[5] << 16);
        uh.w = hh[6] | (hh[7] << 16);
        ul.x = ll[0] | (ll[1] << 16);
        ul.y = ll[2] | (ll[3] << 16);
        ul.z = ll[4] | (ll[5] << 16);
        ul.w = ll[6] | (ll[7] << 16);
        wfh[idx] = uh;
        wfl[idx] = ul;
    }
}

// ---------------------------------------------------------------------------
// parallel scan phase A: per-1024-chunk sums
__global__ void chunk_sums(const int* __restrict__ cnt, int* __restrict__ bsum) {
    __shared__ int ws[16];
    int tid = threadIdx.x;
    int lane = tid & 63;
    int wid = tid >> 6;
    int v = cnt[blockIdx.x * 1024 + tid];
#pragma unroll
    for (int off = 32; off >= 1; off >>= 1) v += __shfl_down(v, off, 64);
    if (lane == 0) ws[wid] = v;
    __syncthreads();
    if (tid < 16) {
        int s = ws[tid];
#pragma unroll
        for (int off = 8; off >= 1; off >>= 1) s += __shfl_down(s, off, 16);
        if (tid == 0) bsum[blockIdx.x] = s;
    }
}

// ---------------------------------------------------------------------------
// scan phase B+C fused: every block scans the 192 chunk sums in LDS (cheap),
// then does its per-chunk scan with the block prefix -> rowptr. One launch.
__global__ void scan_chunks2(const int* __restrict__ cnt, const int* __restrict__ bsum,
                             int* __restrict__ rowptr) {
    __shared__ int sb[192];
    __shared__ int wsum[16];
    int tid = threadIdx.x;
    int lane = tid & 63;
    int wid = tid >> 6;
    if (tid < 192) sb[tid] = bsum[tid];
    __syncthreads();
    // Hillis-Steele inclusive scan over 192 entries
    for (int off = 1; off < 192; off <<= 1) {
        int v = (tid < 192 && tid >= off) ? sb[tid - off] : 0;
        __syncthreads();
        if (tid < 192) sb[tid] += v;
        __syncthreads();
    }
    const int bpre = (blockIdx.x == 0) ? 0 : sb[blockIdx.x - 1];
    int base = blockIdx.x * 1024;
    int v = cnt[base + tid];
    int x = v;
#pragma unroll
    for (int off = 1; off < 64; off <<= 1) {
        int t = __shfl_up(x, off, 64);
        if (lane >= off) x += t;
    }
    if (lane == 63) wsum[wid] = x;
    __syncthreads();
    if (wid == 0 && lane < 16) {
        int s = wsum[lane];
        int y = s;
#pragma unroll
        for (int off = 1; off < 16; off <<= 1) {
            int t = __shfl_up(y, off, 16);
            if (lane >= off) y += t;
        }
        wsum[lane] = y - s;
    }
    __syncthreads();
    int excl = x - v + wsum[wid] + bpre;
    rowptr[base + tid] = excl;
    if (blockIdx.x == 191 && tid == 1023) rowptr[V] = excl + v;
}

// ---------------------------------------------------------------------------
// XCD-partitioned rank scatter (r12-proven): block b handles edge slice b>>3,
// writes only positions in window (b&7) of cev. No atomics.
__global__ void scatter_rank(const int* __restrict__ rows, const int* __restrict__ cols,
                             const float* __restrict__ vals, const int* __restrict__ rowptr,
                             const int* __restrict__ rank, int2* __restrict__ cev) {
    const int slice = blockIdx.x >> 3;
    const int w = blockIdx.x & 7;
    const int lo = w * (NNZ / 8);
    const int hi = lo + (NNZ / 8);
    const int base = slice * EDGES_PER_SLICE;
#pragma unroll 2
    for (int i = threadIdx.x; i < EDGES_PER_SLICE; i += 256) {
        int e = base + i;
        int p = rowptr[rows[e]] + rank[e];
        if (p >= lo && p < hi) {
            int2 pk;
            pk.x = cols[e];
            pk.y = __float_as_int(vals[e]);
            cev[p] = pk;
        }
    }
}

// ---------------------------------------------------------------------------
// bf16 gather SpMM v3.1: persistent waves, 2 rows per iteration, joint 4+4
// strip-mine (8 gathers in flight), then solo 4-strips before 2/1 drains.
template <int COMBINE>
__global__ __launch_bounds__(256) void spmm_gather(
    const int* __restrict__ rowptr, const int2* __restrict__ cev,
    const unsigned int* __restrict__ x, const unsigned int* __restrict__ xm2,
    unsigned int* __restrict__ y) {
    const int lane = threadIdx.x & 63;
    const int wid0 = (blockIdx.x * 256 + threadIdx.x) >> 6;
    const int NW = SPMM_BLOCKS * 4;  // total waves
    for (int base = wid0 * 2; base < V; base += NW * 2) {
        const int r0 = base, r1 = base + 1;
        const int s0 = rowptr[r0];
        const int e0 = rowptr[r0 + 1];
        const int e1 = rowptr[r1 + 1];  // s1 == e0
        float ax0 = 0.f, ay0 = 0.f, ax1 = 0.f, ay1 = 0.f;
        int i0 = s0, i1 = e0;
        while (e0 - i0 >= 4 && e1 - i1 >= 4) {
            int2 Ea[4], Eb[4];
#pragma unroll
            for (int j = 0; j < 4; ++j) {
                Ea[j] = cev[i0 + j];
                Eb[j] = cev[i1 + j];
            }
            unsigned int Ua[4], Ub[4];
#pragma unroll
            for (int j = 0; j < 4; ++j) {
                Ua[j] = x[(size_t)Ea[j].x * ROWU + lane];
                Ub[j] = x[(size_t)Eb[j].x * ROWU + lane];
            }
#pragma unroll
            for (int j = 0; j < 4; ++j) {
                float va = __int_as_float(Ea[j].y);
                float vb = __int_as_float(Eb[j].y);
                ax0 = fmaf(va, bflo(Ua[j]), ax0);
                ay0 = fmaf(va, bfhi(Ua[j]), ay0);
                ax1 = fmaf(vb, bflo(Ub[j]), ax1);
                ay1 = fmaf(vb, bfhi(Ub[j]), ay1);
            }
            i0 += 4;
            i1 += 4;
        }
        while (e0 - i0 >= 4) {
            int2 Ea[4];
#pragma unroll
            for (int j = 0; j < 4; ++j) Ea[j] = cev[i0 + j];
            unsigned int Ua[4];
#pragma unroll
            for (int j = 0; j < 4; ++j) Ua[j] = x[(size_t)Ea[j].x * ROWU + lane];
#pragma unroll
            for (int j = 0; j < 4; ++j) {
                float va = __int_as_float(Ea[j].y);
                ax0 = fmaf(va, bflo(Ua[j]), ax0);
                ay0 = fmaf(va, bfhi(Ua[j]), ay0);
            }
            i0 += 4;
        }
        while (e1 - i1 >= 4) {
            int2 Eb[4];
#pragma unroll
            for (int j = 0; j < 4; ++j) Eb[j] = cev[i1 + j];
            unsigned int Ub[4];
#pragma unroll
            for (int j = 0; j < 4; ++j) Ub[j] = x[(size_t)Eb[j].x * ROWU + lane];
#pragma unroll
            for (int j = 0; j < 4; ++j) {
                float vb = __int_as_float(Eb[j].y);
                ax1 = fmaf(vb, bflo(Ub[j]), ax1);
                ay1 = fmaf(vb, bfhi(Ub[j]), ay1);
            }
            i1 += 4;
        }
        for (; i0 + 2 <= e0; i0 += 2) {
            int2 a = cev[i0], b = cev[i0 + 1];
            unsigned int u0 = x[(size_t)a.x * ROWU + lane];
            unsigned int u1 = x[(size_t)b.x * ROWU + lane];
            float v0 = __int_as_float(a.y), v1 = __int_as_float(b.y);
            ax0 = fmaf(v0, bflo(u0), ax0);
            ay0 = fmaf(v0, bfhi(u0), ay0);
            ax0 = fmaf(v1, bflo(u1), ax0);
            ay0 = fmaf(v1, bfhi(u1), ay0);
        }
        for (; i0 < e0; ++i0) {
            int2 a = cev[i0];
            unsigned int u = x[(size_t)a.x * ROWU + lane];
            float v = __int_as_float(a.y);
            ax0 = fmaf(v, bflo(u), ax0);
            ay0 = fmaf(v, bfhi(u), ay0);
        }
        for (; i1 + 2 <= e1; i1 += 2) {
            int2 a = cev[i1], b = cev[i1 + 1];
            unsigned int u0 = x[(size_t)a.x * ROWU + lane];
            unsigned int u1 = x[(size_t)b.x * ROWU + lane];
            float v0 = __int_as_float(a.y), v1 = __int_as_float(b.y);
            ax1 = fmaf(v0, bflo(u0), ax1);
            ay1 = fmaf(v0, bfhi(u0), ay1);
            ax1 = fmaf(v1, bflo(u1), ax1);
            ay1 = fmaf(v1, bfhi(u1), ay1);
        }
        for (; i1 < e1; ++i1) {
            int2 a = cev[i1];
            unsigned int u = x[(size_t)a.x * ROWU + lane];
            float v = __int_as_float(a.y);
            ax1 = fmaf(v, bflo(u), ax1);
            ay1 = fmaf(v, bfhi(u), ay1);
        }
        if (COMBINE) {
            unsigned int m0 = xm2[(size_t)r0 * ROWU + lane];
            unsigned int m1 = xm2[(size_t)r1 * ROWU + lane];
            ax0 = 2.0f * ax0 - bflo(m0);
            ay0 = 2.0f * ay0 - bfhi(m0);
            ax1 = 2.0f * ax1 - bflo(m1);
            ay1 = 2.0f * ay1 - bfhi(m1);
        }
        y[(size_t)r0 * ROWU + lane] = f2bf(ax0) | (f2bf(ay0) << 16);
        y[(size_t)r1 * ROWU + lane] = f2bf(ax1) | (f2bf(ay1) << 16);
    }
}

// ---------------------------------------------------------------------------
// MFMA fused output contraction. Wave = 16 vertices x 64 outs x 4 batches.
// A-frag: lane l holds x[v0+(l&15)][b*32 + (l>>4)*8 .. +8]  (one 16B load)
// C/D:    col=lane&15, row=(lane>>4)*4+reg   [m89-verified mapping]
__global__ __launch_bounds__(256) void fused_mfma(
    const unsigned short* __restrict__ x0, const unsigned short* __restrict__ x1,
    const unsigned short* __restrict__ x2, const unsigned short* __restrict__ x3,
    const unsigned short* __restrict__ x4, const uint4* __restrict__ wfh,
    const uint4* __restrict__ wfl, const float* __restrict__ bias,
    float* __restrict__ out) {
    const int tid = threadIdx.x;
    const int lane = tid & 63;
    const int g = (blockIdx.x * 256 + tid) >> 6;
    const int v0 = g << 4;
    const int col = lane & 15;
    const int quad = lane >> 4;
    const unsigned short* const xs[K] = {x0, x1, x2, x3, x4};

    f32x4 acc[B][4];
#pragma unroll
    for (int b = 0; b < B; ++b)
#pragma unroll
        for (int nt = 0; nt < 4; ++nt) acc[b][nt] = (f32x4){0.f, 0.f, 0.f, 0.f};

#pragma unroll
    for (int k = 0; k < K; ++k) {
        const unsigned short* xk = xs[k] + ((size_t)(v0 + col)) * C + quad * 8;
        bf16x8 a0 = *reinterpret_cast<const bf16x8*>(xk);
        bf16x8 a1 = *reinterpret_cast<const bf16x8*>(xk + 32);
        bf16x8 a2 = *reinterpret_cast<const bf16x8*>(xk + 64);
        bf16x8 a3 = *reinterpret_cast<const bf16x8*>(xk + 96);
#pragma unroll
        for (int nt = 0; nt < 4; ++nt) {
            uint4 uh = wfh[(k * 4 + nt) * 64 + lane];
            uint4 ul = wfl[(k * 4 + nt) * 64 + lane];
            bf16x8 wh = *reinterpret_cast<bf16x8*>(&uh);
            bf16x8 wl = *reinterpret_cast<bf16x8*>(&ul);
            acc[0][nt] = __builtin_amdgcn_mfma_f32_16x16x32_bf16(a0, wh, acc[0][nt], 0, 0, 0);
            acc[1][nt] = __builtin_amdgcn_mfma_f32_16x16x32_bf16(a1, wh, acc[1][nt], 0, 0, 0);
            acc[2][nt] = __builtin_amdgcn_mfma_f32_16x16x32_bf16(a2, wh, acc[2][nt], 0, 0, 0);
            acc[3][nt] = __builtin_amdgcn_mfma_f32_16x16x32_bf16(a3, wh, acc[3][nt], 0, 0, 0);
            acc[0][nt] = __builtin_amdgcn_mfma_f32_16x16x32_bf16(a0, wl, acc[0][nt], 0, 0, 0);
            acc[1][nt] = __builtin_amdgcn_mfma_f32_16x16x32_bf16(a1, wl, acc[1][nt], 0, 0, 0);
            acc[2][nt] = __builtin_amdgcn_mfma_f32_16x16x32_bf16(a2, wl, acc[2][nt], 0, 0, 0);
            acc[3][nt] = __builtin_amdgcn_mfma_f32_16x16x32_bf16(a3, wl, acc[3][nt], 0, 0, 0);
        }
    }

    float bv[4];
#pragma unroll
    for (int nt = 0; nt < 4; ++nt) bv[nt] = bias[nt * 16 + col];
#pragma unroll
    for (int b = 0; b < B; ++b)
#pragma unroll
        for (int nt = 0; nt < 4; ++nt)
#pragma unroll
            for (int r = 0; r < 4; ++r) {
                int row = quad * 4 + r;
                out[((size_t)b * V + v0 + row) * FOUT + nt * 16 + col] = acc[b][nt][r] + bv[nt];
            }
}

// ---------------------------------------------------------------------------
extern "C" void kernel_launch(void* const* d_in, const int* in_sizes, int n_in,
                              void* d_out, int out_size, void* d_ws, size_t ws_size,
                              hipStream_t stream) {
    const int* lap_rows = (const int*)d_in[0];
    const int* lap_cols = (const int*)d_in[1];
    const float* lap_vals = (const float*)d_in[2];
    const float* inputs = (const float*)d_in[3];
    const float* weight = (const float*)d_in[4];  // flat [160][64] == effective W
    const float* bias = (const float*)d_in[5];
    float* out = (float*)d_out;

    char* p = (char*)d_ws;
    auto alloc = [&](size_t bytes) {
        char* r = p;
        p += (bytes + 511) & ~(size_t)511;
        return r;
    };
    int* rowptr = (int*)alloc((size_t)(V + 1) * 4);
    int* cnt = (int*)alloc((size_t)V * 4);
    int* bsum = (int*)alloc(192 * 4);
    int* rank = (int*)alloc((size_t)NNZ * 4);
    uint4* wfh = (uint4*)alloc((size_t)K * 4 * 64 * 16);
    uint4* wfl = (uint4*)alloc((size_t)K * 4 * 64 * 16);
    int2* cev = (int2*)alloc((size_t)NNZ * 8);
    unsigned int* xb0 = (unsigned int*)alloc((size_t)V * ROWU * 4);
    unsigned int* xb1 = (unsigned int*)alloc((size_t)V * ROWU * 4);
    unsigned int* xb2 = (unsigned int*)alloc((size_t)V * ROWU * 4);
    unsigned int* xb3 = (unsigned int*)alloc((size_t)V * ROWU * 4);
    unsigned int* xb4 = (unsigned int*)alloc((size_t)V * ROWU * 4);

    const int mfma_blocks = (V / 16) * 64 / 256; // 3072
    const int prep_blocks = HIST_BLOCKS + X0_BLOCKS + WFRAG_BLOCKS;  // 19205

    // ---- CSR build + prep (fused, 4 dispatches) ----
    zero_cursor<<<(V / 4 + 255) / 256, 256, 0, stream>>>((uint4*)cnt);
    prep_fused<<<prep_blocks, 256, 0, stream>>>(lap_rows, cnt, rank, inputs, (uint4*)xb0,
                                                weight, wfh, wfl);
    chunk_sums<<<V / 1024, 1024, 0, stream>>>(cnt, bsum);
    scan_chunks2<<<V / 1024, 1024, 0, stream>>>(cnt, bsum, rowptr);
    scatter_rank<<<NSLICE * 8, 256, 0, stream>>>(lap_rows, lap_cols, lap_vals, rowptr,
                                                 rank, cev);

    // ---- Chebyshev recurrence (bf16 storage, f32 accumulate) ----
    spmm_gather<0><<<SPMM_BLOCKS, 256, 0, stream>>>(rowptr, cev, xb0, nullptr, xb1);
    spmm_gather<1><<<SPMM_BLOCKS, 256, 0, stream>>>(rowptr, cev, xb1, xb0, xb2);
    spmm_gather<1><<<SPMM_BLOCKS, 256, 0, stream>>>(rowptr, cev, xb2, xb1, xb3);
    spmm_gather<1><<<SPMM_BLOCKS, 256, 0, stream>>>(rowptr, cev, xb3, xb2, xb4);

    // ---- fused MFMA output contraction ----
    fused_mfma<<<mfma_blocks, 256, 0, stream>>>(
        (const unsigned short*)xb0, (const unsigned short*)xb1, (const unsigned short*)xb2,
        (const unsigned short*)xb3, (const unsigned short*)xb4, wfh, wfl, bias, out);
}